// Round 16
// baseline (219.280 us; speedup 1.0000x reference)
//
#include <hip/hip_runtime.h>

#define SEQ 2048
#define DIM 1024
#define NHEAD 16
#define HDIM 64
#define NTOK 4096   // b*s
#define N3D 3072

typedef __attribute__((ext_vector_type(8))) short bf16x8;
typedef __attribute__((ext_vector_type(4))) float floatx4;
typedef __attribute__((ext_vector_type(4))) unsigned short ushortx4;

__device__ __forceinline__ unsigned short f2bf(float f) {
    unsigned int u = __builtin_bit_cast(unsigned int, f);
    u += 0x7FFFu + ((u >> 16) & 1u);
    return (unsigned short)(u >> 16);
}

// async global->LDS, 16B per lane. LDS dest must be wave-uniform base + lane*16.
__device__ __forceinline__ void async_copy16(const void* g, const void* l) {
    __builtin_amdgcn_global_load_lds(
        (const __attribute__((address_space(1))) unsigned int*)(unsigned long long)g,
        (__attribute__((address_space(3))) unsigned int*)(unsigned int)(unsigned long long)l,
        16, 0, 0);
}

#define MFMA_BF16(a, b, c) __builtin_amdgcn_mfma_f32_16x16x32_bf16((a), (b), (c), 0, 0, 0)

// ---------------------------------------------------------------------------
// Fused prep: weight transposes (fp32->bf16) + LayerNorm + logt bias table.
// ---------------------------------------------------------------------------
__global__ __launch_bounds__(256)
void prep_kernel(const float* __restrict__ w_qkv, unsigned short* __restrict__ wqkvT,
                 const float* __restrict__ w_out, unsigned short* __restrict__ woutT,
                 const float* __restrict__ x, const float* __restrict__ gamma,
                 const float* __restrict__ lnb, unsigned short* __restrict__ xn,
                 const float* __restrict__ betap, float* __restrict__ logt_g) {
    const int bid = blockIdx.x;
    const int tid = threadIdx.x;
    if (bid >= 8192) {
        const float betaV = betap[0];
        const float L2E = 1.44269504f;
        int i = (bid - 8192) * 256 + tid;            // 0..1023
        logt_g[i] = betaV * log1pf((float)i) * L2E - 20.0f;
        logt_g[i + 1024] = betaV * log1pf((float)(i + 1024)) * L2E - 20.0f;
        return;
    }
    if (bid < 4096) {
        __shared__ float tile[32][33];
        const float* src; unsigned short* dst; int cols, bx, by;
        if (bid < 3072) { src = w_qkv; dst = wqkvT; cols = N3D; bx = bid % 96; by = bid / 96; }
        else { int t = bid - 3072; src = w_out; dst = woutT; cols = DIM; bx = t & 31; by = t >> 5; }
        const int c0 = bx * 32, r0 = by * 32;
        const int tx = tid & 31, ty = tid >> 5;  // 32 x 8
        for (int i = 0; i < 4; ++i) {
            int r = ty + i * 8;
            tile[r][tx] = src[(size_t)(r0 + r) * cols + c0 + tx];
        }
        __syncthreads();
        for (int i = 0; i < 4; ++i) {
            int rr = ty + i * 8;  // col index in src
            dst[(size_t)(c0 + rr) * DIM + r0 + tx] = f2bf(tile[tx][rr]);
        }
    } else {
        const int row = bid - 4096;
        const float* xr = x + (size_t)row * DIM;
        float4 v = ((const float4*)xr)[tid];
        float s = v.x + v.y + v.z + v.w;
        float s2 = v.x * v.x + v.y * v.y + v.z * v.z + v.w * v.w;
        for (int off = 1; off < 64; off <<= 1) {
            s += __shfl_xor(s, off, 64);
            s2 += __shfl_xor(s2, off, 64);
        }
        __shared__ float red[8];
        const int wave = tid >> 6, lane = tid & 63;
        if (lane == 0) { red[wave] = s; red[4 + wave] = s2; }
        __syncthreads();
        s = red[0] + red[1] + red[2] + red[3];
        s2 = red[4] + red[5] + red[6] + red[7];
        const float mu = s * (1.0f / DIM);
        const float var = s2 * (1.0f / DIM) - mu * mu;
        const float rstd = rsqrtf(var + 1e-5f);
        float4 g = ((const float4*)gamma)[tid];
        float4 bb = ((const float4*)lnb)[tid];
        unsigned short* o = xn + (size_t)row * DIM + tid * 4;
        o[0] = f2bf((v.x - mu) * rstd * g.x + bb.x);
        o[1] = f2bf((v.y - mu) * rstd * g.y + bb.y);
        o[2] = f2bf((v.z - mu) * rstd * g.z + bb.z);
        o[3] = f2bf((v.w - mu) * rstd * g.w + bb.w);
    }
}

// ---------------------------------------------------------------------------
// QKV GEMM (FROZEN R15 measured-best: 256x192, BK=64, 8 waves, dbuf 2-phase,
// 256 wgs = 1 block/CU zero tail, LDS 112 KB, XCD-chunked).
// Scatters q,k -> [b,h,s,hd]; v -> [b,h,hd,s].
// ---------------------------------------------------------------------------
__global__ __launch_bounds__(512)
void qkv_gemm(const unsigned short* __restrict__ A, const unsigned short* __restrict__ Bt,
              const float* __restrict__ bias, unsigned short* __restrict__ qo,
              unsigned short* __restrict__ ko, unsigned short* __restrict__ vTo) {
    __shared__ unsigned short Asm[2][256 * 64];   // 64 KB
    __shared__ unsigned short Bsm[2][192 * 64];   // 48 KB
    const int tid = threadIdx.x;
    const int wave = tid >> 6, lane = tid & 63;
    const int quad = lane >> 4, r16 = lane & 15;
    const int flat = blockIdx.x;
    const int xcd = flat & 7, c = flat >> 3;           // c in [0,32)
    const int mt = (xcd >> 1) * 4 + (c >> 3);          // [0,16)
    const int nt = (xcd & 1) * 8 + (c & 7);            // [0,16)
    const int m0 = mt * 256, n0 = nt * 192;
    const int wm = (wave & 1) * 128, wn = (wave >> 1) * 48;
    floatx4 acc[8][3] = {};
    for (int p = 0; p < 4; ++p) {
        int s = tid + p * 512;          // [0,2048): 256 rows x 8 slots
        async_copy16(A + (size_t)(m0 + (s >> 3)) * DIM + ((s & 7) << 3), &Asm[0][s * 8]);
    }
    for (int p = 0; p < 3; ++p) {
        int s = tid + p * 512;          // [0,1536): 192 rows x 8 slots
        async_copy16(Bt + (size_t)(n0 + (s >> 3)) * DIM + ((s & 7) << 3), &Bsm[0][s * 8]);
    }
    __syncthreads();
    for (int it = 0; it < 16; ++it) {
        const int cur = it & 1;
        if (it + 1 < 16) {
            const int k1 = (it + 1) * 64;
            for (int p = 0; p < 4; ++p) {
                int s = tid + p * 512;
                async_copy16(A + (size_t)(m0 + (s >> 3)) * DIM + k1 + ((s & 7) << 3),
                             &Asm[cur ^ 1][s * 8]);
            }
            for (int p = 0; p < 3; ++p) {
                int s = tid + p * 512;
                async_copy16(Bt + (size_t)(n0 + (s >> 3)) * DIM + k1 + ((s & 7) << 3),
                             &Bsm[cur ^ 1][s * 8]);
            }
        }
        for (int h = 0; h < 2; ++h) {
            bf16x8 af[8], bfr[3];
            for (int i = 0; i < 8; ++i)
                af[i] = *(const bf16x8*)(&Asm[cur][(wm + i * 16 + r16) * 64 + h * 32 + quad * 8]);
            for (int j = 0; j < 3; ++j)
                bfr[j] = *(const bf16x8*)(&Bsm[cur][(wn + j * 16 + r16) * 64 + h * 32 + quad * 8]);
            for (int i = 0; i < 8; ++i)
                for (int j = 0; j < 3; ++j)
                    acc[i][j] = MFMA_BF16(af[i], bfr[j], acc[i][j]);
        }
        __syncthreads();
    }
    for (int j = 0; j < 3; ++j) {
        int n = n0 + wn + j * 16 + r16;
        float bn = bias[n];
        int part = n >> 10, nn = n & 1023;
        int head = nn >> 6, hdi = nn & 63;
        for (int i = 0; i < 8; ++i) {
            int mbase = m0 + wm + i * 16 + quad * 4;
            int bIdx = mbase >> 11, sIdx = mbase & 2047;
            if (part == 2) {
                ushortx4 pack;
                for (int e = 0; e < 4; ++e) pack[e] = f2bf(acc[i][j][e] + bn);
                *(ushortx4*)(vTo + ((size_t)(bIdx * NHEAD + head) * HDIM + hdi) * SEQ + sIdx) = pack;
            } else {
                unsigned short* dst = (part == 0) ? qo : ko;
                for (int e = 0; e < 4; ++e)
                    dst[((size_t)(bIdx * NHEAD + head) * SEQ + sIdx + e) * HDIM + hdi] =
                        f2bf(acc[i][j][e] + bn);
            }
        }
    }
}

// ---------------------------------------------------------------------------
// Flash attention with log1p distance bias.
// Round-16: QBLK 128 -> 256 (same mechanism as R15's qkv win). 8 waves x 32
// q-rows each (two 16-row groups A/B); grid 256 wgs = 1 block/CU, 8 waves =
// 2/SIMD (qkv's winning regime). 36 MFMA/iter/wave vs 18, same staging+
// barrier cost/iter; per-bh K/V staging sweep HALVES (8 blocks vs 16 — the
// inverse of R13's regression). K frags loaded once per iter, reused by both
// groups; V frags likewise. Q direct global->reg (R13-proven). LDS: P scratch
// 256x72 (36.9KB) + K/V dbuf 32KB = 69.6KB. Sync skeleton unchanged.
// grid: 256 1D, XCD-chunked (32/XCD -> 4 bh per XCD).
// ---------------------------------------------------------------------------
__global__ __launch_bounds__(512)
void attn_kernel(const unsigned short* __restrict__ qg, const unsigned short* __restrict__ kg,
                 const unsigned short* __restrict__ vTg, const float* __restrict__ logt,
                 unsigned short* __restrict__ ctx) {
    __shared__ unsigned short QP[256][72];      // wave-private P scratch (144B rows)
    __shared__ unsigned short Kd[2][64 * 64];   // swizzled, rows=key
    __shared__ unsigned short Vd[2][64 * 64];   // swizzled, rows=d (V^T)

    const int tid = threadIdx.x;
    const int wave = tid >> 6, lane = tid & 63;
    const int quad = lane >> 4, r16 = lane & 15;
    // XCD swizzle: 256 wgs, 32/XCD -> bh span of 4 per XCD
    const int flat = blockIdx.x;
    const int swz = (flat & 7) * 32 + (flat >> 3);
    const int bh = swz >> 3, qt = swz & 7;
    const int qBase = qt * 256;
    const float L2E = 1.44269504f;
    const float c1 = 0.125f * L2E;

    // Q fragments: one-time direct global load (registers thereafter)
    const unsigned short* qptr = qg + ((size_t)bh * SEQ + qBase) * HDIM;
    const int qr0 = wave * 32 + r16;            // group A row (local)
    bf16x8 qf0a = *(const bf16x8*)(qptr + qr0 * HDIM + quad * 8);
    bf16x8 qf1a = *(const bf16x8*)(qptr + qr0 * HDIM + 32 + quad * 8);
    bf16x8 qf0b = *(const bf16x8*)(qptr + (qr0 + 16) * HDIM + quad * 8);
    bf16x8 qf1b = *(const bf16x8*)(qptr + (qr0 + 16) * HDIM + 32 + quad * 8);

    // async-stage K/V chunk 0 into buf 0 (swizzled: colgrp (j&7)^(r&7))
    const int sr = tid >> 3;
    const int scg = (tid & 7) ^ (sr & 7);
    const unsigned short* kbh = kg + (size_t)bh * SEQ * HDIM;
    const unsigned short* vbh = vTg + (size_t)bh * HDIM * SEQ;
    async_copy16(kbh + (size_t)sr * HDIM + scg * 8, &Kd[0][tid * 8]);
    async_copy16(vbh + (size_t)sr * SEQ + scg * 8, &Vd[0][tid * 8]);
    __syncthreads();

    const bf16x8 onesv = {0x3F80, 0x3F80, 0x3F80, 0x3F80, 0x3F80, 0x3F80, 0x3F80, 0x3F80};

    floatx4 oa[5] = {}, ob[5] = {};   // [4] = row sums (ones trick)
    const int qWB0 = qBase + wave * 32;            // group A base (wave-uniform)
    const int qWB1 = qWB0 + 16;                    // group B base (wave-uniform)
    const int qrTa = qWB0 + r16;
    const int qrTb = qWB1 + r16;
    unsigned short* prowA = &QP[wave * 32 + r16][0];
    unsigned short* prowB = &QP[wave * 32 + 16 + r16][0];

    for (int kt0 = 0; kt0 < SEQ; kt0 += 64) {
        const int buf = (kt0 >> 6) & 1;
        if (kt0 + 64 < SEQ) {
            async_copy16(kbh + (size_t)(kt0 + 64 + sr) * HDIM + scg * 8, &Kd[buf ^ 1][tid * 8]);
            async_copy16(vbh + (size_t)sr * SEQ + kt0 + 64 + scg * 8, &Vd[buf ^ 1][tid * 8]);
        }

        // K fragments: load once, reuse for both q-row groups
        bf16x8 kf0[4], kf1[4];
        for (int ct = 0; ct < 4; ++ct) {
            int rK = ct * 16 + r16;
            const unsigned short* kb = &Kd[buf][rK * 64];
            kf0[ct] = *(const bf16x8*)(kb + ((quad ^ (rK & 7)) << 3));
            kf1[ct] = *(const bf16x8*)(kb + (((quad ^ 4) ^ (rK & 7)) << 3));
        }

        floatx4 sca[4], scb[4];
        __builtin_amdgcn_s_setprio(1);
        for (int ct = 0; ct < 4; ++ct) {
            floatx4 z = {0.f, 0.f, 0.f, 0.f};
            z = MFMA_BF16(kf0[ct], qf0a, z);
            z = MFMA_BF16(kf1[ct], qf1a, z);
            sca[ct] = z;
            floatx4 w = {0.f, 0.f, 0.f, 0.f};
            w = MFMA_BF16(kf0[ct], qf0b, w);
            w = MFMA_BF16(kf1[ct], qf1b, w);
            scb[ct] = w;
        }
        __builtin_amdgcn_s_setprio(0);

        // softmax + P-pack, group A then B (log2 domain, fixed -20 offset)
        for (int g = 0; g < 2; ++g) {
            floatx4* sc = g ? scb : sca;
            const int qWB = g ? qWB1 : qWB0;
            const int qrT = g ? qrTb : qrTa;
            unsigned short* prow = g ? prowB : prowA;
            for (int ct = 0; ct < 4; ++ct) {
                const int keyTile = kt0 + ct * 16;      // wave-uniform
                const int kbase = keyTile + quad * 4;
                if (qWB >= keyTile + 16) {              // all queries > all keys
                    const float* lp = &logt[qrT - kbase - 3];
                    for (int i = 0; i < 4; ++i)
                        sc[ct][i] = __builtin_amdgcn_exp2f(sc[ct][i] * c1 + lp[3 - i]);
                } else if (keyTile >= qWB + 16) {       // all keys > all queries
                    const float* lp = &logt[kbase - qrT];
                    for (int i = 0; i < 4; ++i)
                        sc[ct][i] = __builtin_amdgcn_exp2f(sc[ct][i] * c1 + lp[i]);
                } else {                                 // mixed (diagonal tiles)
                    for (int i = 0; i < 4; ++i) {
                        int dist = qrT - (kbase + i);
                        dist = dist < 0 ? -dist : dist;
                        sc[ct][i] = __builtin_amdgcn_exp2f(sc[ct][i] * c1 + logt[dist]);
                    }
                }
            }
            for (int ct = 0; ct < 4; ++ct) {
                unsigned int lo, hi;
                asm("v_cvt_pk_bf16_f32 %0, %1, %2" : "=v"(lo) : "v"(sc[ct][0]), "v"(sc[ct][1]));
                asm("v_cvt_pk_bf16_f32 %0, %1, %2" : "=v"(hi) : "v"(sc[ct][2]), "v"(sc[ct][3]));
                uint2 pk; pk.x = lo; pk.y = hi;
                *(uint2*)(prow + ct * 16 + quad * 4) = pk;   // 8B-aligned (144B rows)
            }
        }
        bf16x8 pf0a = *(const bf16x8*)(prowA + quad * 8);
        bf16x8 pf1a = *(const bf16x8*)(prowA + 32 + quad * 8);
        bf16x8 pf0b = *(const bf16x8*)(prowB + quad * 8);
        bf16x8 pf1b = *(const bf16x8*)(prowB + 32 + quad * 8);
        // PV: V frags loaded once, reused by both groups (+ ones row sums)
        __builtin_amdgcn_s_setprio(1);
        for (int nt = 0; nt < 4; ++nt) {
            int rV = nt * 16 + r16;
            const unsigned short* vb = &Vd[buf][rV * 64];
            bf16x8 vf0 = *(const bf16x8*)(vb + ((quad ^ (rV & 7)) << 3));
            bf16x8 vf1 = *(const bf16x8*)(vb + (((quad ^ 4) ^ (rV & 7)) << 3));
            oa[nt] = MFMA_BF16(pf0a, vf0, oa[nt]);
            oa[nt] = MFMA_BF16(pf1a, vf1, oa[nt]);
            ob[nt] = MFMA_BF16(pf0b, vf0, ob[nt]);
            ob[nt] = MFMA_BF16(pf1b, vf1, ob[nt]);
        }
        oa[4] = MFMA_BF16(pf0a, onesv, oa[4]);
        oa[4] = MFMA_BF16(pf1a, onesv, oa[4]);
        ob[4] = MFMA_BF16(pf0b, onesv, ob[4]);
        ob[4] = MFMA_BF16(pf1b, onesv, ob[4]);
        __builtin_amdgcn_s_setprio(0);

        __syncthreads();
    }

    const int b_ = bh >> 4, h_ = bh & 15;
    for (int i = 0; i < 4; ++i) {
        float inva = 1.0f / oa[4][i];
        float invb = 1.0f / ob[4][i];
        int qiA = qBase + wave * 32 + quad * 4 + i;
        int qiB = qiA + 16;
        for (int nt = 0; nt < 4; ++nt) {
            int d = nt * 16 + r16;
            ctx[((size_t)(b_ * SEQ + qiA)) * DIM + h_ * HDIM + d] = f2bf(oa[nt][i] * inva);
            ctx[((size_t)(b_ * SEQ + qiB)) * DIM + h_ * HDIM + d] = f2bf(ob[nt][i] * invb);
        }
    }
}

// ---------------------------------------------------------------------------
// Out projection + bias + residual: out = ctx @ w_out + b_out + x  (fp32 out)
// (FROZEN R6 measured-best: dbuf prefetch, 128x64 tiles, 512 wgs = 2
// blocks/CU, XCD-chunked swizzle.)
// ---------------------------------------------------------------------------
__global__ __launch_bounds__(256)
void out_gemm(const unsigned short* __restrict__ A, const unsigned short* __restrict__ Bt,
              const float* __restrict__ bias, const float* __restrict__ resid,
              float* __restrict__ out) {
    __shared__ unsigned short Asm[2][128 * 64];   // 32 KB
    __shared__ unsigned short Bsm[2][64 * 64];    // 16 KB
    const int tid = threadIdx.x;
    const int wave = tid >> 6, lane = tid & 63;
    const int quad = lane >> 4, r16 = lane & 15;
    const int flat = blockIdx.y * 16 + blockIdx.x;
    const int swz = (flat & 7) * 64 + (flat >> 3);
    const int m0 = (swz >> 4) * 128, n0 = (swz & 15) * 64;
    const int wm = (wave & 1) * 64, wn = (wave >> 1) * 32;
    floatx4 acc[4][2] = {};
    for (int p = 0; p < 4; ++p) {
        int s = tid + p * 256;
        async_copy16(A + (size_t)(m0 + (s >> 3)) * DIM + ((s & 7) << 3), &Asm[0][s * 8]);
    }
    for (int p = 0; p < 2; ++p) {
        int s = tid + p * 256;
        async_copy16(Bt + (size_t)(n0 + (s >> 3)) * DIM + ((s & 7) << 3), &Bsm[0][s * 8]);
    }
    __syncthreads();
    for (int it = 0; it < 16; ++it) {
        const int cur = it & 1;
        if (it + 1 < 16) {
            const int k1 = (it + 1) * 64;
            for (int p = 0; p < 4; ++p) {
                int s = tid + p * 256;
                async_copy16(A + (size_t)(m0 + (s >> 3)) * DIM + k1 + ((s & 7) << 3),
                             &Asm[cur ^ 1][s * 8]);
            }
            for (int p = 0; p < 2; ++p) {
                int s = tid + p * 256;
                async_copy16(Bt + (size_t)(n0 + (s >> 3)) * DIM + k1 + ((s & 7) << 3),
                             &Bsm[cur ^ 1][s * 8]);
            }
        }
        for (int h = 0; h < 2; ++h) {
            bf16x8 af[4], bfr[2];
            for (int i = 0; i < 4; ++i)
                af[i] = *(const bf16x8*)(&Asm[cur][(wm + i * 16 + r16) * 64 + h * 32 + quad * 8]);
            for (int j = 0; j < 2; ++j)
                bfr[j] = *(const bf16x8*)(&Bsm[cur][(wn + j * 16 + r16) * 64 + h * 32 + quad * 8]);
            for (int i = 0; i < 4; ++i)
                for (int j = 0; j < 2; ++j)
                    acc[i][j] = MFMA_BF16(af[i], bfr[j], acc[i][j]);
        }
        __syncthreads();
    }
    for (int i = 0; i < 4; ++i)
        for (int j = 0; j < 2; ++j)
            for (int e = 0; e < 4; ++e) {
                int m = m0 + wm + i * 16 + quad * 4 + e;
                int n = n0 + wn + j * 16 + r16;
                out[(size_t)m * DIM + n] = acc[i][j][e] + bias[n] + resid[(size_t)m * DIM + n];
            }
}

// ---------------------------------------------------------------------------
extern "C" void kernel_launch(void* const* d_in, const int* in_sizes, int n_in,
                              void* d_out, int out_size, void* d_ws, size_t ws_size,
                              hipStream_t stream) {
    const float* x     = (const float*)d_in[0];
    const float* w_qkv = (const float*)d_in[1];
    const float* b_qkv = (const float*)d_in[2];
    const float* w_out = (const float*)d_in[3];
    const float* b_out = (const float*)d_in[4];
    const float* gamma = (const float*)d_in[5];
    const float* ln_b  = (const float*)d_in[6];
    const float* beta  = (const float*)d_in[7];
    float* out = (float*)d_out;

    char* ws = (char*)d_ws;
    const size_t MB = 1u << 20;
    unsigned short* xn    = (unsigned short*)(ws);            // 8 MB (reused as ctx)
    unsigned short* wqkvT = (unsigned short*)(ws + 8 * MB);   // 6 MB
    unsigned short* woutT = (unsigned short*)(ws + 14 * MB);  // 2 MB
    unsigned short* qb    = (unsigned short*)(ws + 16 * MB);  // 8 MB
    unsigned short* kb    = (unsigned short*)(ws + 24 * MB);  // 8 MB
    unsigned short* vTb   = (unsigned short*)(ws + 32 * MB);  // 8 MB
    float* logt_g         = (float*)(ws + 40 * MB);           // 8 KB
    unsigned short* ctx   = xn;  // xn dead after qkv_gemm; safe alias (stream-ordered)

    prep_kernel<<<8196, 256, 0, stream>>>(w_qkv, wqkvT, w_out, woutT, x, gamma, ln_b, xn,
                                          beta, logt_g);
    qkv_gemm<<<256, 512, 0, stream>>>(xn, wqkvT, b_qkv, qb, kb, vTb);
    attn_kernel<<<256, 512, 0, stream>>>(qb, kb, vTb, logt_g, ctx);
    out_gemm<<<dim3(16, 32), 256, 0, stream>>>(ctx, woutT, b_out, x, out);
}

// Round 18
// 201.326 us; speedup vs baseline: 1.0892x; 1.0892x over previous
//
#include <hip/hip_runtime.h>

#define SEQ 2048
#define DIM 1024
#define NHEAD 16
#define HDIM 64
#define NTOK 4096   // b*s
#define N3D 3072

typedef __attribute__((ext_vector_type(8))) short bf16x8;
typedef __attribute__((ext_vector_type(4))) float floatx4;
typedef __attribute__((ext_vector_type(4))) unsigned short ushortx4;

__device__ __forceinline__ unsigned short f2bf(float f) {
    unsigned int u = __builtin_bit_cast(unsigned int, f);
    u += 0x7FFFu + ((u >> 16) & 1u);
    return (unsigned short)(u >> 16);
}

// async global->LDS, 16B per lane. LDS dest must be wave-uniform base + lane*16.
__device__ __forceinline__ void async_copy16(const void* g, const void* l) {
    __builtin_amdgcn_global_load_lds(
        (const __attribute__((address_space(1))) unsigned int*)(unsigned long long)g,
        (__attribute__((address_space(3))) unsigned int*)(unsigned int)(unsigned long long)l,
        16, 0, 0);
}

#define MFMA_BF16(a, b, c) __builtin_amdgcn_mfma_f32_16x16x32_bf16((a), (b), (c), 0, 0, 0)

// ---------------------------------------------------------------------------
// Fused prep: weight transposes (fp32->bf16) + LayerNorm + logt bias table.
// ---------------------------------------------------------------------------
__global__ __launch_bounds__(256)
void prep_kernel(const float* __restrict__ w_qkv, unsigned short* __restrict__ wqkvT,
                 const float* __restrict__ w_out, unsigned short* __restrict__ woutT,
                 const float* __restrict__ x, const float* __restrict__ gamma,
                 const float* __restrict__ lnb, unsigned short* __restrict__ xn,
                 const float* __restrict__ betap, float* __restrict__ logt_g) {
    const int bid = blockIdx.x;
    const int tid = threadIdx.x;
    if (bid >= 8192) {
        const float betaV = betap[0];
        const float L2E = 1.44269504f;
        int i = (bid - 8192) * 256 + tid;            // 0..1023
        logt_g[i] = betaV * log1pf((float)i) * L2E - 20.0f;
        logt_g[i + 1024] = betaV * log1pf((float)(i + 1024)) * L2E - 20.0f;
        return;
    }
    if (bid < 4096) {
        __shared__ float tile[32][33];
        const float* src; unsigned short* dst; int cols, bx, by;
        if (bid < 3072) { src = w_qkv; dst = wqkvT; cols = N3D; bx = bid % 96; by = bid / 96; }
        else { int t = bid - 3072; src = w_out; dst = woutT; cols = DIM; bx = t & 31; by = t >> 5; }
        const int c0 = bx * 32, r0 = by * 32;
        const int tx = tid & 31, ty = tid >> 5;  // 32 x 8
        for (int i = 0; i < 4; ++i) {
            int r = ty + i * 8;
            tile[r][tx] = src[(size_t)(r0 + r) * cols + c0 + tx];
        }
        __syncthreads();
        for (int i = 0; i < 4; ++i) {
            int rr = ty + i * 8;  // col index in src
            dst[(size_t)(c0 + rr) * DIM + r0 + tx] = f2bf(tile[tx][rr]);
        }
    } else {
        const int row = bid - 4096;
        const float* xr = x + (size_t)row * DIM;
        float4 v = ((const float4*)xr)[tid];
        float s = v.x + v.y + v.z + v.w;
        float s2 = v.x * v.x + v.y * v.y + v.z * v.z + v.w * v.w;
        for (int off = 1; off < 64; off <<= 1) {
            s += __shfl_xor(s, off, 64);
            s2 += __shfl_xor(s2, off, 64);
        }
        __shared__ float red[8];
        const int wave = tid >> 6, lane = tid & 63;
        if (lane == 0) { red[wave] = s; red[4 + wave] = s2; }
        __syncthreads();
        s = red[0] + red[1] + red[2] + red[3];
        s2 = red[4] + red[5] + red[6] + red[7];
        const float mu = s * (1.0f / DIM);
        const float var = s2 * (1.0f / DIM) - mu * mu;
        const float rstd = rsqrtf(var + 1e-5f);
        float4 g = ((const float4*)gamma)[tid];
        float4 bb = ((const float4*)lnb)[tid];
        unsigned short* o = xn + (size_t)row * DIM + tid * 4;
        o[0] = f2bf((v.x - mu) * rstd * g.x + bb.x);
        o[1] = f2bf((v.y - mu) * rstd * g.y + bb.y);
        o[2] = f2bf((v.z - mu) * rstd * g.z + bb.z);
        o[3] = f2bf((v.w - mu) * rstd * g.w + bb.w);
    }
}

// ---------------------------------------------------------------------------
// QKV GEMM (FROZEN R15 measured-best: 256x192, BK=64, 8 waves, dbuf 2-phase,
// 256 wgs = 1 block/CU zero tail, LDS 112 KB, XCD-chunked).
// Scatters q,k -> [b,h,s,hd]; v -> [b,h,hd,s].
// ---------------------------------------------------------------------------
__global__ __launch_bounds__(512)
void qkv_gemm(const unsigned short* __restrict__ A, const unsigned short* __restrict__ Bt,
              const float* __restrict__ bias, unsigned short* __restrict__ qo,
              unsigned short* __restrict__ ko, unsigned short* __restrict__ vTo) {
    __shared__ unsigned short Asm[2][256 * 64];   // 64 KB
    __shared__ unsigned short Bsm[2][192 * 64];   // 48 KB
    const int tid = threadIdx.x;
    const int wave = tid >> 6, lane = tid & 63;
    const int quad = lane >> 4, r16 = lane & 15;
    const int flat = blockIdx.x;
    const int xcd = flat & 7, c = flat >> 3;           // c in [0,32)
    const int mt = (xcd >> 1) * 4 + (c >> 3);          // [0,16)
    const int nt = (xcd & 1) * 8 + (c & 7);            // [0,16)
    const int m0 = mt * 256, n0 = nt * 192;
    const int wm = (wave & 1) * 128, wn = (wave >> 1) * 48;
    floatx4 acc[8][3] = {};
    for (int p = 0; p < 4; ++p) {
        int s = tid + p * 512;          // [0,2048): 256 rows x 8 slots
        async_copy16(A + (size_t)(m0 + (s >> 3)) * DIM + ((s & 7) << 3), &Asm[0][s * 8]);
    }
    for (int p = 0; p < 3; ++p) {
        int s = tid + p * 512;          // [0,1536): 192 rows x 8 slots
        async_copy16(Bt + (size_t)(n0 + (s >> 3)) * DIM + ((s & 7) << 3), &Bsm[0][s * 8]);
    }
    __syncthreads();
    for (int it = 0; it < 16; ++it) {
        const int cur = it & 1;
        if (it + 1 < 16) {
            const int k1 = (it + 1) * 64;
            for (int p = 0; p < 4; ++p) {
                int s = tid + p * 512;
                async_copy16(A + (size_t)(m0 + (s >> 3)) * DIM + k1 + ((s & 7) << 3),
                             &Asm[cur ^ 1][s * 8]);
            }
            for (int p = 0; p < 3; ++p) {
                int s = tid + p * 512;
                async_copy16(Bt + (size_t)(n0 + (s >> 3)) * DIM + k1 + ((s & 7) << 3),
                             &Bsm[cur ^ 1][s * 8]);
            }
        }
        for (int h = 0; h < 2; ++h) {
            bf16x8 af[8], bfr[3];
            for (int i = 0; i < 8; ++i)
                af[i] = *(const bf16x8*)(&Asm[cur][(wm + i * 16 + r16) * 64 + h * 32 + quad * 8]);
            for (int j = 0; j < 3; ++j)
                bfr[j] = *(const bf16x8*)(&Bsm[cur][(wn + j * 16 + r16) * 64 + h * 32 + quad * 8]);
            for (int i = 0; i < 8; ++i)
                for (int j = 0; j < 3; ++j)
                    acc[i][j] = MFMA_BF16(af[i], bfr[j], acc[i][j]);
        }
        __syncthreads();
    }
    for (int j = 0; j < 3; ++j) {
        int n = n0 + wn + j * 16 + r16;
        float bn = bias[n];
        int part = n >> 10, nn = n & 1023;
        int head = nn >> 6, hdi = nn & 63;
        for (int i = 0; i < 8; ++i) {
            int mbase = m0 + wm + i * 16 + quad * 4;
            int bIdx = mbase >> 11, sIdx = mbase & 2047;
            if (part == 2) {
                ushortx4 pack;
                for (int e = 0; e < 4; ++e) pack[e] = f2bf(acc[i][j][e] + bn);
                *(ushortx4*)(vTo + ((size_t)(bIdx * NHEAD + head) * HDIM + hdi) * SEQ + sIdx) = pack;
            } else {
                unsigned short* dst = (part == 0) ? qo : ko;
                for (int e = 0; e < 4; ++e)
                    dst[((size_t)(bIdx * NHEAD + head) * SEQ + sIdx + e) * HDIM + hdi] =
                        f2bf(acc[i][j][e] + bn);
            }
        }
    }
}

// ---------------------------------------------------------------------------
// Flash attention with log1p distance bias.
// R12/R15 measured-best config (QBLK=128, 512 threads, 512 wgs = 2 blocks/CU
// — R16 proved attn NEEDS >=2 independent blocks/CU because its serial
// softmax phase can't interleave within one barrier-locked block).
// Micro: Q fragments direct global->reg (proven R13/R16), Q-staging loop
// removed; QP retained solely as wave-private P scratch.
// grid: (SEQ/128, B*NHEAD), 512 threads.
// ---------------------------------------------------------------------------
__global__ __launch_bounds__(512)
void attn_kernel(const unsigned short* __restrict__ qg, const unsigned short* __restrict__ kg,
                 const unsigned short* __restrict__ vTg, const float* __restrict__ logt,
                 unsigned short* __restrict__ ctx) {
    __shared__ unsigned short QP[128][72];      // wave-private P scratch (144B rows)
    __shared__ unsigned short Kd[2][64 * 64];   // swizzled, rows=key
    __shared__ unsigned short Vd[2][64 * 64];   // swizzled, rows=d (V^T)

    const int tid = threadIdx.x;
    const int wave = tid >> 6, lane = tid & 63;
    const int quad = lane >> 4, r16 = lane & 15;
    // XCD swizzle: flat dispatch id -> chunked (bh, qt) (nwg=512, 64 per XCD)
    const int flat = blockIdx.y * 16 + blockIdx.x;
    const int swz = (flat & 7) * 64 + (flat >> 3);
    const int bh = swz >> 4, qt = swz & 15;
    const int qBase = qt * 128;
    const float L2E = 1.44269504f;
    const float c1 = 0.125f * L2E;

    // Q fragments: one-time direct global load (registers thereafter)
    const unsigned short* qptr = qg + ((size_t)bh * SEQ + qBase) * HDIM;
    const int qrow = wave * 16 + r16;
    bf16x8 qf0 = *(const bf16x8*)(qptr + qrow * HDIM + quad * 8);
    bf16x8 qf1 = *(const bf16x8*)(qptr + qrow * HDIM + 32 + quad * 8);

    // async-stage K/V chunk 0 into buf 0 (swizzled: colgrp (j&7)^(r&7))
    const int sr = tid >> 3;
    const int scg = (tid & 7) ^ (sr & 7);
    const unsigned short* kbh = kg + (size_t)bh * SEQ * HDIM;
    const unsigned short* vbh = vTg + (size_t)bh * HDIM * SEQ;
    async_copy16(kbh + (size_t)sr * HDIM + scg * 8, &Kd[0][tid * 8]);
    async_copy16(vbh + (size_t)sr * SEQ + scg * 8, &Vd[0][tid * 8]);
    __syncthreads();

    const bf16x8 onesv = {0x3F80, 0x3F80, 0x3F80, 0x3F80, 0x3F80, 0x3F80, 0x3F80, 0x3F80};

    floatx4 o[5] = {};   // o[4] accumulates row sums (ones trick)
    const int qWaveBase = qBase + wave * 16;       // wave-uniform
    const int qrT = qWaveBase + r16;               // this thread's q-row (swapped layout)

    for (int kt0 = 0; kt0 < SEQ; kt0 += 64) {
        const int buf = (kt0 >> 6) & 1;
        if (kt0 + 64 < SEQ) {
            async_copy16(kbh + (size_t)(kt0 + 64 + sr) * HDIM + scg * 8, &Kd[buf ^ 1][tid * 8]);
            async_copy16(vbh + (size_t)sr * SEQ + kt0 + 64 + scg * 8, &Vd[buf ^ 1][tid * 8]);
        }

        // QK^T, swapped: D[key][qrow]; lane holds keys keyTile+quad*4+{0..3}, qrow=r16
        floatx4 sc[4];
        __builtin_amdgcn_s_setprio(1);
        for (int ct = 0; ct < 4; ++ct) {
            int rK = ct * 16 + r16;
            const unsigned short* kb = &Kd[buf][rK * 64];
            bf16x8 kf0 = *(const bf16x8*)(kb + ((quad ^ (rK & 7)) << 3));
            bf16x8 kf1 = *(const bf16x8*)(kb + (((quad ^ 4) ^ (rK & 7)) << 3));
            floatx4 z = {0.f, 0.f, 0.f, 0.f};
            z = MFMA_BF16(kf0, qf0, z);   // A=K (k-chunk [0,32)), B=Q
            z = MFMA_BF16(kf1, qf1, z);   // A=K (k-chunk [32,64)), B=Q
            sc[ct] = z;
        }
        __builtin_amdgcn_s_setprio(0);
        // scale + distance bias (log2 domain, fixed -20 offset in table), exp2 -> p.
        for (int ct = 0; ct < 4; ++ct) {
            const int keyTile = kt0 + ct * 16;      // wave-uniform
            const int kbase = keyTile + quad * 4;   // first of this lane's 4 keys
            if (qWaveBase >= keyTile + 16) {        // all queries > all keys
                const float* lp = &logt[qrT - kbase - 3];   // dist = (qrT-kbase) - i
                for (int i = 0; i < 4; ++i)
                    sc[ct][i] = __builtin_amdgcn_exp2f(sc[ct][i] * c1 + lp[3 - i]);
            } else if (keyTile >= qWaveBase + 16) { // all keys > all queries
                const float* lp = &logt[kbase - qrT];       // dist = (kbase-qrT) + i
                for (int i = 0; i < 4; ++i)
                    sc[ct][i] = __builtin_amdgcn_exp2f(sc[ct][i] * c1 + lp[i]);
            } else {                                 // mixed (diagonal tiles)
                for (int i = 0; i < 4; ++i) {
                    int dist = qrT - (kbase + i);
                    dist = dist < 0 ? -dist : dist;
                    sc[ct][i] = __builtin_amdgcn_exp2f(sc[ct][i] * c1 + logt[dist]);
                }
            }
        }
        // P: pack 4 consecutive keys (RNE via v_cvt_pk_bf16_f32) -> one b64 store.
        {
            unsigned short* prow = &QP[wave * 16 + r16][0];
            for (int ct = 0; ct < 4; ++ct) {
                unsigned int lo, hi;
                asm("v_cvt_pk_bf16_f32 %0, %1, %2" : "=v"(lo) : "v"(sc[ct][0]), "v"(sc[ct][1]));
                asm("v_cvt_pk_bf16_f32 %0, %1, %2" : "=v"(hi) : "v"(sc[ct][2]), "v"(sc[ct][3]));
                uint2 pk; pk.x = lo; pk.y = hi;
                *(uint2*)(prow + ct * 16 + quad * 4) = pk;   // 8B-aligned (144B rows)
            }
        }
        bf16x8 pf0 = *(const bf16x8*)(&QP[wave * 16 + r16][quad * 8]);
        bf16x8 pf1 = *(const bf16x8*)(&QP[wave * 16 + r16][32 + quad * 8]);
        // PV (+ ones tile for row sums)
        __builtin_amdgcn_s_setprio(1);
        for (int nt = 0; nt < 4; ++nt) {
            int rV = nt * 16 + r16;
            const unsigned short* vb = &Vd[buf][rV * 64];
            bf16x8 vf0 = *(const bf16x8*)(vb + ((quad ^ (rV & 7)) << 3));
            bf16x8 vf1 = *(const bf16x8*)(vb + (((quad ^ 4) ^ (rV & 7)) << 3));
            o[nt] = MFMA_BF16(pf0, vf0, o[nt]);
            o[nt] = MFMA_BF16(pf1, vf1, o[nt]);
        }
        o[4] = MFMA_BF16(pf0, onesv, o[4]);
        o[4] = MFMA_BF16(pf1, onesv, o[4]);
        __builtin_amdgcn_s_setprio(0);

        __syncthreads();
    }

    const int b_ = bh >> 4, h_ = bh & 15;
    for (int i = 0; i < 4; ++i) {
        float inv = 1.0f / o[4][i];
        int qi = qBase + wave * 16 + quad * 4 + i;
        for (int nt = 0; nt < 4; ++nt) {
            int d = nt * 16 + r16;
            ctx[((size_t)(b_ * SEQ + qi)) * DIM + h_ * HDIM + d] = f2bf(o[nt][i] * inv);
        }
    }
}

// ---------------------------------------------------------------------------
// Out projection + bias + residual: out = ctx @ w_out + b_out + x  (fp32 out)
// (FROZEN R6 measured-best: dbuf prefetch, 128x64 tiles, 512 wgs = 2
// blocks/CU, XCD-chunked swizzle.)
// ---------------------------------------------------------------------------
__global__ __launch_bounds__(256)
void out_gemm(const unsigned short* __restrict__ A, const unsigned short* __restrict__ Bt,
              const float* __restrict__ bias, const float* __restrict__ resid,
              float* __restrict__ out) {
    __shared__ unsigned short Asm[2][128 * 64];   // 32 KB
    __shared__ unsigned short Bsm[2][64 * 64];    // 16 KB
    const int tid = threadIdx.x;
    const int wave = tid >> 6, lane = tid & 63;
    const int quad = lane >> 4, r16 = lane & 15;
    const int flat = blockIdx.y * 16 + blockIdx.x;
    const int swz = (flat & 7) * 64 + (flat >> 3);
    const int m0 = (swz >> 4) * 128, n0 = (swz & 15) * 64;
    const int wm = (wave & 1) * 64, wn = (wave >> 1) * 32;
    floatx4 acc[4][2] = {};
    for (int p = 0; p < 4; ++p) {
        int s = tid + p * 256;
        async_copy16(A + (size_t)(m0 + (s >> 3)) * DIM + ((s & 7) << 3), &Asm[0][s * 8]);
    }
    for (int p = 0; p < 2; ++p) {
        int s = tid + p * 256;
        async_copy16(Bt + (size_t)(n0 + (s >> 3)) * DIM + ((s & 7) << 3), &Bsm[0][s * 8]);
    }
    __syncthreads();
    for (int it = 0; it < 16; ++it) {
        const int cur = it & 1;
        if (it + 1 < 16) {
            const int k1 = (it + 1) * 64;
            for (int p = 0; p < 4; ++p) {
                int s = tid + p * 256;
                async_copy16(A + (size_t)(m0 + (s >> 3)) * DIM + k1 + ((s & 7) << 3),
                             &Asm[cur ^ 1][s * 8]);
            }
            for (int p = 0; p < 2; ++p) {
                int s = tid + p * 256;
                async_copy16(Bt + (size_t)(n0 + (s >> 3)) * DIM + k1 + ((s & 7) << 3),
                             &Bsm[cur ^ 1][s * 8]);
            }
        }
        for (int h = 0; h < 2; ++h) {
            bf16x8 af[4], bfr[2];
            for (int i = 0; i < 4; ++i)
                af[i] = *(const bf16x8*)(&Asm[cur][(wm + i * 16 + r16) * 64 + h * 32 + quad * 8]);
            for (int j = 0; j < 2; ++j)
                bfr[j] = *(const bf16x8*)(&Bsm[cur][(wn + j * 16 + r16) * 64 + h * 32 + quad * 8]);
            for (int i = 0; i < 4; ++i)
                for (int j = 0; j < 2; ++j)
                    acc[i][j] = MFMA_BF16(af[i], bfr[j], acc[i][j]);
        }
        __syncthreads();
    }
    for (int i = 0; i < 4; ++i)
        for (int j = 0; j < 2; ++j)
            for (int e = 0; e < 4; ++e) {
                int m = m0 + wm + i * 16 + quad * 4 + e;
                int n = n0 + wn + j * 16 + r16;
                out[(size_t)m * DIM + n] = acc[i][j][e] + bias[n] + resid[(size_t)m * DIM + n];
            }
}

// ---------------------------------------------------------------------------
extern "C" void kernel_launch(void* const* d_in, const int* in_sizes, int n_in,
                              void* d_out, int out_size, void* d_ws, size_t ws_size,
                              hipStream_t stream) {
    const float* x     = (const float*)d_in[0];
    const float* w_qkv = (const float*)d_in[1];
    const float* b_qkv = (const float*)d_in[2];
    const float* w_out = (const float*)d_in[3];
    const float* b_out = (const float*)d_in[4];
    const float* gamma = (const float*)d_in[5];
    const float* ln_b  = (const float*)d_in[6];
    const float* beta  = (const float*)d_in[7];
    float* out = (float*)d_out;

    char* ws = (char*)d_ws;
    const size_t MB = 1u << 20;
    unsigned short* xn    = (unsigned short*)(ws);            // 8 MB (reused as ctx)
    unsigned short* wqkvT = (unsigned short*)(ws + 8 * MB);   // 6 MB
    unsigned short* woutT = (unsigned short*)(ws + 14 * MB);  // 2 MB
    unsigned short* qb    = (unsigned short*)(ws + 16 * MB);  // 8 MB
    unsigned short* kb    = (unsigned short*)(ws + 24 * MB);  // 8 MB
    unsigned short* vTb   = (unsigned short*)(ws + 32 * MB);  // 8 MB
    float* logt_g         = (float*)(ws + 40 * MB);           // 8 KB
    unsigned short* ctx   = xn;  // xn dead after qkv_gemm; safe alias (stream-ordered)

    prep_kernel<<<8196, 256, 0, stream>>>(w_qkv, wqkvT, w_out, woutT, x, gamma, ln_b, xn,
                                          beta, logt_g);
    qkv_gemm<<<256, 512, 0, stream>>>(xn, wqkvT, b_qkv, qb, kb, vTb);
    attn_kernel<<<dim3(SEQ / 128, 32), 512, 0, stream>>>(qb, kb, vTb, logt_g, ctx);
    out_gemm<<<dim3(16, 32), 256, 0, stream>>>(ctx, woutT, b_out, x, out);
}